// Round 22
// baseline (68.828 us; speedup 1.0000x reference)
//
#include <hip/hip_runtime.h>
#include <math.h>

#define F 128
#define HID 32
#define NH 4
#define TILE 32
#define ROWB 512  // bytes per fp32 row (128 * 4)

typedef __attribute__((ext_vector_type(8))) short bf16x8;
typedef __attribute__((ext_vector_type(4))) float f32x4;

__device__ __forceinline__ float silu_f(float x) {
    return x / (1.0f + __expf(-x));
}

__device__ __forceinline__ uint f2bf(float f) {  // RNE float->bf16 (one-time W1 prep)
    union { float f; uint u; } v; v.f = f;
    uint r = v.u + 0x7fffu + ((v.u >> 16) & 1u);
    return r >> 16;
}

__device__ __forceinline__ uint cvtpk_bf16(float lo, float hi) {  // HW RNE pack
    uint r;
    asm("v_cvt_pk_bf16_f32 %0, %1, %2" : "=v"(r) : "v"(lo), "v"(hi));
    return r;
}

__device__ __forceinline__ void gload_lds16(const void* g, void* l) {
    // async 16B global->LDS; LDS dest is wave-uniform base + lane*16
    __builtin_amdgcn_global_load_lds(
        (const __attribute__((address_space(1))) void*)g,
        (__attribute__((address_space(3))) void*)l, 16, 0, 0);
}

// Wave-parallel 64-ary lower_bound: first index i in [0,N] with seg[i] >= v.
__device__ __forceinline__ int lower_bound_wave(const int* __restrict__ seg, int N,
                                                int v, int lane) {
    int lo = 0, hi = N;
    while (hi - lo > 64) {
        const int step = ((hi - lo) + 63) >> 6;
        const int idx = lo + lane * step;
        const bool inr = (idx < hi);
        const int val = inr ? seg[idx] : 0;
        const unsigned long long m = __ballot(inr && (val < v));
        const int cnt = __popcll(m);
        if (cnt == 0) return lo;
        const int probe_hi = lo + cnt * step;
        lo = lo + (cnt - 1) * step + 1;
        hi = (probe_hi < hi) ? probe_hi : hi;
    }
    const int idx = lo + lane;
    const bool inr = (idx < hi);
    const int val = inr ? seg[idx] : 0;
    const unsigned long long m = __ballot(inr && (val < v));
    return lo + __popcll(m);
}

// R21 structure with the s_run bug fixed: phase D ownership matches phase-C
// atom-range ownership (wave wv owns atoms [8wv,8wv+8) x ALL heads), so phase
// C uses broadcast reads (tile read once, not 4x) with NO extra barrier.
// FIX vs R21: s_run is per-(ao,ch) lane state -> reduce over ao lanes
// (shfl_xor 4/8/16) before the epilogue per-head store.
__global__ __launch_bounds__(256, 4) void fused19_kernel(
    const float* __restrict__ atom_fea, const int* __restrict__ seg, int N,
    const float* __restrict__ W1, const float* __restrict__ b1,
    const float* __restrict__ W2, const float* __restrict__ b2,
    const float* __restrict__ Wp, const float* __restrict__ bp,
    float* __restrict__ out) {
    __shared__ float sStage[2][TILE * F];  // 2 x 16 KB, 16B-chunk XOR swizzle (^ row&7)
    __shared__ float sP[2 * TILE * 5];     // partial logits [half][atom][head], stride 5
    __shared__ float sTW[NH][8 * NH];      // exp weights [wave][atom_off*4+head], 512 B
    __shared__ float sEpi[NH][520];        // epilogue merge [wave][512 acc | 4 m | 4 s]

    const int t = threadIdx.x;
    const int b = blockIdx.x;
    const int wv = t >> 6;
    const int lane = t & 63;
    const int lg = lane >> 4;
    const int l15 = lane & 15;
    const int ag = wv & 1;        // MFMA atom-group (atoms 16ag..16ag+15)
    const int mh = wv >> 1;       // MFMA hid-half (hids 16mh..16mh+15)
    const int ch = lane & 3;      // D+C: head
    const int ao = (lane >> 2) & 7;   // D: atom offset in wave's 8-atom range
    const int co = lane >> 2;     // C: feat-oct (feats 8co..8co+7), 0..15

    // ---- segment bounds: wave-parallel search (redundant per wave) ----
    const int start = lower_bound_wave(seg, N, b, lane);
    const int end = lower_bound_wave(seg, N, b + 1, lane);

    // per-thread DMA slots (inverse-swizzled source; read-side XOR recovers)
    int roff[4], coff[4];
    #pragma unroll
    for (int i = 0; i < 4; ++i) {
        const int q = i * 256 + t;
        roff[i] = q >> 5;
        coff[i] = ((q & 31) ^ (roff[i] & 7)) << 4;
    }

    // ---- one-time register preloads: this wave's hid-half of W1T ----
    bf16x8 w1f[4];
    #pragma unroll
    for (int kk = 0; kk < 4; ++kk) {
        bf16x8 fr;
        #pragma unroll
        for (int j = 0; j < 8; ++j)
            fr[j] = (short)f2bf(W1[(kk * 32 + lg * 8 + j) * HID + mh * 16 + l15]);
        w1f[kk] = fr;
    }
    float b1r[4], w2r[4][4];
    #pragma unroll
    for (int r = 0; r < 4; ++r) {
        const int h = mh * 16 + lg * 4 + r;
        b1r[r] = b1[h];
        #pragma unroll
        for (int j = 0; j < 4; ++j) w2r[r][j] = W2[h * NH + j];
    }
    const float b2r0 = b2[0], b2r1 = b2[1], b2r2 = b2[2], b2r3 = b2[3];
    const float b2h = (ch & 1) ? ((ch & 2) ? b2r3 : b2r1) : ((ch & 2) ? b2r2 : b2r0);

    float m_run = -INFINITY;  // (wave, head) running max (uniform across same-ch lanes)
    float s_run = 0.0f;       // PER-(ao,ch) denom partial; reduced over ao at epilogue
    float acc8[8] = {0, 0, 0, 0, 0, 0, 0, 0};  // (head ch, feats 8co..+8), wv's atoms

    const int nt = (end > start) ? (end - start + TILE - 1) / TILE : 0;
    const char* gbase = (const char*)atom_fea;

    // ---- prologue: DMA tile 0 into buf0 ----
    if (nt > 0) {
        #pragma unroll
        for (int i = 0; i < 4; ++i) {
            int a = start + roff[i]; a = (a < end) ? a : end - 1;  // clamp rows
            gload_lds16(gbase + (size_t)a * ROWB + coff[i],
                        (char*)sStage[0] + i * 4096 + wv * 1024);
        }
    }
    __syncthreads();  // drains vmcnt(0): tile 0 staged

    int pb = 0;
    for (int ti = 0; ti < nt; ++ti) {
        const int base = start + ti * TILE;
        const int T = min(TILE, end - base);
        const char* bufc = (const char*)sStage[pb];
        const bool has_next = (ti + 1 < nt);  // block-uniform

        // ---- issue DMA(k+1) into alternate buffer (in flight whole tile) ----
        if (has_next) {
            const int nbase = base + TILE;
            char* ldst = (char*)sStage[pb ^ 1];
            #pragma unroll
            for (int i = 0; i < 4; ++i) {
                int a = nbase + roff[i]; a = (a < end) ? a : end - 1;
                gload_lds16(gbase + (size_t)a * ROWB + coff[i],
                            ldst + i * 4096 + wv * 1024);
            }
        }

        // ---- B: MFMA MLP; wave (ag, mh): atoms 16ag..+16, hids 16mh..+16 ----
        {
            f32x4 acc;
            #pragma unroll
            for (int r = 0; r < 4; ++r) acc[r] = b1r[r];
            const int row = ag * 16 + l15;
            const char* rb = bufc + row * ROWB;
            const int rs = row & 7;
            #pragma unroll
            for (int kk = 0; kk < 4; ++kk) {
                const int c0 = kk * 8 + lg * 2;
                const float4 va = *(const float4*)(rb + ((c0 ^ rs) << 4));
                const float4 vb = *(const float4*)(rb + (((c0 + 1) ^ rs) << 4));
                union { bf16x8 v; uint u[4]; } fr;
                fr.u[0] = cvtpk_bf16(va.x, va.y);
                fr.u[1] = cvtpk_bf16(va.z, va.w);
                fr.u[2] = cvtpk_bf16(vb.x, vb.y);
                fr.u[3] = cvtpk_bf16(vb.z, vb.w);
                acc = __builtin_amdgcn_mfma_f32_16x16x32_bf16(w1f[kk], fr.v, acc, 0, 0, 0);
            }
            float p0 = 0, p1 = 0, p2 = 0, p3 = 0;
            #pragma unroll
            for (int r = 0; r < 4; ++r) {
                const float s = silu_f(acc[r]);
                p0 = fmaf(s, w2r[r][0], p0);
                p1 = fmaf(s, w2r[r][1], p1);
                p2 = fmaf(s, w2r[r][2], p2);
                p3 = fmaf(s, w2r[r][3], p3);
            }
            p0 += __shfl_xor(p0, 16); p0 += __shfl_xor(p0, 32);
            p1 += __shfl_xor(p1, 16); p1 += __shfl_xor(p1, 32);
            p2 += __shfl_xor(p2, 16); p2 += __shfl_xor(p2, 32);
            p3 += __shfl_xor(p3, 16); p3 += __shfl_xor(p3, 32);
            if (lane < 16) {
                float* d = &sP[(mh * TILE + ag * 16 + lane) * 5];
                d[0] = p0; d[1] = p1; d[2] = p2; d[3] = p3;
            }
        }
        // bar1: LDS-only fence (NO vmcnt drain -> DMA keeps streaming)
        asm volatile("s_waitcnt lgkmcnt(0)" ::: "memory");
        __builtin_amdgcn_s_barrier();

        // ---- D: defer-max softmax; wave wv owns atoms [8wv,8wv+8) x ALL heads;
        //      lane = (ao, ch) replicated x2; max state per (wave, head) ----
        {
            const int a = wv * 8 + ao;
            const bool valid = (a < T);
            const float v = valid
                ? sP[a * 5 + ch] + sP[(TILE + a) * 5 + ch] + b2h
                : -INFINITY;
            if (__any(v > m_run + 8.0f)) {  // rare after first tile
                float mt = v;
                // reduce over same-head lanes (strides 4,8,16 + replica 32)
                mt = fmaxf(mt, __shfl_xor(mt, 4));
                mt = fmaxf(mt, __shfl_xor(mt, 8));
                mt = fmaxf(mt, __shfl_xor(mt, 16));
                mt = fmaxf(mt, __shfl_xor(mt, 32));
                const float m_new = fmaxf(m_run, mt);
                const float r = __expf(m_run - m_new);  // first tile: exp(-inf)=0
                s_run *= r;
                #pragma unroll
                for (int j = 0; j < 8; ++j) acc8[j] *= r;
                m_run = m_new;
            }
            const float e = valid ? __expf(v - m_run) : 0.0f;  // bounded by e^8
            if (lane < 32) sTW[wv][ao * NH + ch] = e;  // own-wave region
            s_run += e;  // per-(ao,ch); reduced over ao at epilogue
        }

        // ---- C: broadcast weighted accumulate; wave wv = atoms [8wv,8wv+8);
        //      lane = (head ch, oct co); whole wave reads ONE row per iter ----
        {
            #pragma unroll 4
            for (int i = 0; i < 8; ++i) {
                const int a = wv * 8 + i;             // wave-uniform row
                const float w = sTW[wv][i * NH + ch]; // 4 addrs, 16-lane broadcast
                const int sw = a & 7;
                const char* ra = bufc + a * ROWB;
                const float4 v0 = *(const float4*)(ra + (((2 * co) ^ sw) << 4));
                const float4 v1 = *(const float4*)(ra + (((2 * co + 1) ^ sw) << 4));
                acc8[0] = fmaf(w, v0.x, acc8[0]);
                acc8[1] = fmaf(w, v0.y, acc8[1]);
                acc8[2] = fmaf(w, v0.z, acc8[2]);
                acc8[3] = fmaf(w, v0.w, acc8[3]);
                acc8[4] = fmaf(w, v1.x, acc8[4]);
                acc8[5] = fmaf(w, v1.y, acc8[5]);
                acc8[6] = fmaf(w, v1.z, acc8[6]);
                acc8[7] = fmaf(w, v1.w, acc8[7]);
            }
        }
        __syncthreads();  // drains vmcnt(0): DMA(k+1) landed; buf[pb] reads done
        pb ^= 1;
    }

    // ---- FIX: fold the per-(ao,ch) denom partials into per-head sums ----
    s_run += __shfl_xor(s_run, 4);
    s_run += __shfl_xor(s_run, 8);
    s_run += __shfl_xor(s_run, 16);
    // (stride-32 replicas hold the same values; lanes 0-3 now have full sums)

    // ---- epilogue 1: merge 4 waves' (m, s, acc) with max-alignment ----
    *(float4*)&sEpi[wv][lane * 8] = make_float4(acc8[0], acc8[1], acc8[2], acc8[3]);
    *(float4*)&sEpi[wv][lane * 8 + 4] = make_float4(acc8[4], acc8[5], acc8[6], acc8[7]);
    if (lane < 4) {  // lane == ch for lanes 0-3
        sEpi[wv][512 + lane] = m_run;
        sEpi[wv][516 + lane] = s_run;
    }
    __syncthreads();
    float* sWacc = (float*)sStage;        // 512 floats, k = h*F + f
    float* sPart = (float*)sStage + 512;  // 256 floats
    if (t < 64) {
        const int ch2 = t & 3, co2 = t >> 2;
        float mw[NH], fw[NH];
        float mg = -INFINITY;
        #pragma unroll
        for (int w = 0; w < NH; ++w) {
            mw[w] = sEpi[w][512 + ch2];
            mg = fmaxf(mg, mw[w]);
        }
        float sg = 0.0f;
        #pragma unroll
        for (int w = 0; w < NH; ++w) {
            fw[w] = (mw[w] == -INFINITY) ? 0.0f : __expf(mw[w] - mg);
            sg += sEpi[w][516 + ch2] * fw[w];
        }
        const float inv = (sg > 0.0f) ? 1.0f / sg : 0.0f;
        float o[8] = {0, 0, 0, 0, 0, 0, 0, 0};
        #pragma unroll
        for (int w = 0; w < NH; ++w) {
            const float* ap = &sEpi[w][t * 8];
            #pragma unroll
            for (int j = 0; j < 8; ++j) o[j] = fmaf(ap[j], fw[w], o[j]);
        }
        float* dst = &sWacc[ch2 * F + co2 * 8];
        #pragma unroll
        for (int j = 0; j < 8; ++j) dst[j] = o[j] * inv;
    }
    __syncthreads();

    // ---- epilogue 2: inline projection out[b] = silu(Wacc @ Wp + bp) ----
    {
        const int f = t & 127, half = t >> 7;
        float sum = 0.0f;
        const float* wp = Wp + (size_t)(half * 256) * F + f;  // lanes coalesced over f
        const float* wa = &sWacc[half * 256];
        for (int k0 = 0; k0 < 256; k0 += 8) {
            float wpv[8];
            #pragma unroll
            for (int u = 0; u < 8; ++u) wpv[u] = wp[(size_t)(k0 + u) * F];
            #pragma unroll
            for (int u = 0; u < 8; ++u) sum = fmaf(wa[k0 + u], wpv[u], sum);
        }
        sPart[t] = sum;
    }
    __syncthreads();
    if (t < 128) out[(size_t)b * F + t] = silu_f(sPart[t] + sPart[t + 128] + bp[t]);
}

extern "C" void kernel_launch(void* const* d_in, const int* in_sizes, int n_in,
                              void* d_out, int out_size, void* d_ws, size_t ws_size,
                              hipStream_t stream) {
    const float* atom_fea = (const float*)d_in[0];
    const int* seg = (const int*)d_in[1];
    const float* W1 = (const float*)d_in[3];
    const float* b1 = (const float*)d_in[4];
    const float* W2 = (const float*)d_in[5];
    const float* b2 = (const float*)d_in[6];
    const float* Wp = (const float*)d_in[7];
    const float* bp = (const float*)d_in[8];
    float* out = (float*)d_out;

    const int N = in_sizes[0] / F;
    const int B = out_size / F;

    fused19_kernel<<<B, 256, 0, stream>>>(atom_fea, seg, N, W1, b1, W2, b2, Wp, bp, out);
}

// Round 23
// 61.635 us; speedup vs baseline: 1.1167x; 1.1167x over previous
//
#include <hip/hip_runtime.h>
#include <math.h>

#define F 128
#define HID 32
#define NH 4
#define TILE 32
#define ROWB 512  // bytes per fp32 row (128 * 4)

typedef __attribute__((ext_vector_type(8))) short bf16x8;
typedef __attribute__((ext_vector_type(4))) float f32x4;

__device__ __forceinline__ float silu_f(float x) {
    return x / (1.0f + __expf(-x));
}

__device__ __forceinline__ uint f2bf(float f) {  // RNE float->bf16 (one-time W1 prep)
    union { float f; uint u; } v; v.f = f;
    uint r = v.u + 0x7fffu + ((v.u >> 16) & 1u);
    return r >> 16;
}

__device__ __forceinline__ uint cvtpk_bf16(float lo, float hi) {  // HW RNE pack
    uint r;
    asm("v_cvt_pk_bf16_f32 %0, %1, %2" : "=v"(r) : "v"(lo), "v"(hi));
    return r;
}

__device__ __forceinline__ void gload_lds16(const void* g, void* l) {
    // async 16B global->LDS; LDS dest is wave-uniform base + lane*16
    __builtin_amdgcn_global_load_lds(
        (const __attribute__((address_space(1))) void*)g,
        (__attribute__((address_space(3))) void*)l, 16, 0, 0);
}

// Wave-parallel 64-ary lower_bound: first index i in [0,N] with seg[i] >= v.
// 3 probe rounds (400K -> 6250 -> ~97) + 1 final round; each round is one
// wave-parallel load + ballot. All lanes return the same value.
__device__ __forceinline__ int lower_bound_wave(const int* __restrict__ seg, int N,
                                                int v, int lane) {
    int lo = 0, hi = N;  // result in [lo, hi]; invariant: lo==0 || seg[lo-1] < v
    while (hi - lo > 64) {
        const int step = ((hi - lo) + 63) >> 6;
        const int idx = lo + lane * step;
        const bool inr = (idx < hi);
        const int val = inr ? seg[idx] : 0;
        const unsigned long long m = __ballot(inr && (val < v));
        const int cnt = __popcll(m);  // probes strictly below v (contiguous from lane 0)
        if (cnt == 0) return lo;      // seg[lo] >= v, invariant -> result == lo
        const int probe_hi = lo + cnt * step;  // first probe with seg >= v (if in range)
        lo = lo + (cnt - 1) * step + 1;
        hi = (probe_hi < hi) ? probe_hi : hi;
    }
    const int idx = lo + lane;
    const bool inr = (idx < hi);
    const int val = inr ? seg[idx] : 0;
    const unsigned long long m = __ballot(inr && (val < v));
    return lo + __popcll(m);
}

// CHAMPION (R20, 61.7 us): single fused kernel for the whole pipeline.
// Structure: block-per-crystal, 32-atom tiles, double-buffered fp32 LDS stage
// via global_load_lds DMA (issue-at-top, in flight the whole tile); MFMA
// 16x16x32 bf16 key-MLP (wave = (atom-group, hid-half), W1T frags in regs);
// defer-max online softmax (T13: steady state = 1 exp + 1 ballot) with
// per-lane deferred denominator; conflict-free XOR-swizzled weighted fp32
// accumulate; in-kernel wave-parallel lower_bound for segment bounds; fused
// output projection epilogue. 2 barriers/tile (bar1 is LDS-only; DMA streams
// across it).
__global__ __launch_bounds__(256, 4) void fused17_kernel(
    const float* __restrict__ atom_fea, const int* __restrict__ seg, int N,
    const float* __restrict__ W1, const float* __restrict__ b1,
    const float* __restrict__ W2, const float* __restrict__ b2,
    const float* __restrict__ Wp, const float* __restrict__ bp,
    float* __restrict__ out) {
    __shared__ float sStage[2][TILE * F];  // 2 x 16 KB, 16B-chunk XOR swizzle (^ row&7)
    __shared__ float sP[2 * TILE * 5];     // partial logits [half][atom][head], stride 5
    __shared__ float sTW[NH * 65];         // exp weights [head][atom]

    const int t = threadIdx.x;
    const int b = blockIdx.x;
    const int wv = t >> 6;
    const int lane = t & 63;
    const int lg = lane >> 4;
    const int l15 = lane & 15;
    const int ag = wv & 1;        // MFMA atom-group (atoms 16ag..16ag+15)
    const int mh = wv >> 1;       // MFMA hid-half (hids 16mh..16mh+15)
    const int ca = lane & 3;      // phase-C atom offset within quad
    const int co = (lane >> 2) & 15;  // phase-C feat-oct (feats 8co..8co+7)

    // ---- segment bounds: wave-parallel search (each wave redundant; no sync) ----
    const int start = lower_bound_wave(seg, N, b, lane);
    const int end = lower_bound_wave(seg, N, b + 1, lane);

    // per-thread DMA slots: slot q holds LDS chunk (r, q&31) from global chunk
    // (q&31)^(r&7) of row r (inverse swizzle; read-side XOR recovers linear)
    int roff[4], coff[4];
    #pragma unroll
    for (int i = 0; i < 4; ++i) {
        const int q = i * 256 + t;
        roff[i] = q >> 5;
        coff[i] = ((q & 31) ^ (roff[i] & 7)) << 4;
    }

    // ---- one-time register preloads: only this wave's hid-half of W1T ----
    bf16x8 w1f[4];  // [k-step]; lane: h'=l15 (of half mh), k'=lg*8+j
    #pragma unroll
    for (int kk = 0; kk < 4; ++kk) {
        bf16x8 fr;
        #pragma unroll
        for (int j = 0; j < 8; ++j)
            fr[j] = (short)f2bf(W1[(kk * 32 + lg * 8 + j) * HID + mh * 16 + l15]);
        w1f[kk] = fr;
    }
    float b1r[4], w2r[4][4];
    #pragma unroll
    for (int r = 0; r < 4; ++r) {
        const int h = mh * 16 + lg * 4 + r;
        b1r[r] = b1[h];
        #pragma unroll
        for (int j = 0; j < 4; ++j) w2r[r][j] = W2[h * NH + j];
    }
    const float b2w = b2[wv];

    float m_run = -INFINITY;
    float s_part = 0.0f;  // per-lane deferred denominator partial
    float acc8[8] = {0, 0, 0, 0, 0, 0, 0, 0};  // head wv, feats 8co..+8, atoms ca mod 4

    const int nt = (end > start) ? (end - start + TILE - 1) / TILE : 0;
    const char* gbase = (const char*)atom_fea;

    // ---- prologue: DMA tile 0 into buf0 ----
    if (nt > 0) {
        #pragma unroll
        for (int i = 0; i < 4; ++i) {
            int a = start + roff[i]; a = (a < end) ? a : end - 1;  // clamp rows
            gload_lds16(gbase + (size_t)a * ROWB + coff[i],
                        (char*)sStage[0] + i * 4096 + wv * 1024);
        }
    }
    __syncthreads();  // drains vmcnt(0): tile 0 staged

    int pb = 0;
    for (int ti = 0; ti < nt; ++ti) {
        const int base = start + ti * TILE;
        const int T = min(TILE, end - base);
        const char* bufc = (const char*)sStage[pb];
        const bool has_next = (ti + 1 < nt);  // block-uniform

        // ---- issue DMA(k+1) into alternate buffer: in flight the WHOLE tile ----
        if (has_next) {
            const int nbase = base + TILE;
            char* ldst = (char*)sStage[pb ^ 1];
            #pragma unroll
            for (int i = 0; i < 4; ++i) {
                int a = nbase + roff[i]; a = (a < end) ? a : end - 1;
                gload_lds16(gbase + (size_t)a * ROWB + coff[i],
                            ldst + i * 4096 + wv * 1024);
            }
        }

        // ---- B: MFMA MLP; wave (ag, mh): atoms 16ag..+16, hids 16mh..+16 ----
        {
            f32x4 acc;
            #pragma unroll
            for (int r = 0; r < 4; ++r) acc[r] = b1r[r];
            const int row = ag * 16 + l15;
            const char* rb = bufc + row * ROWB;
            const int rs = row & 7;
            #pragma unroll
            for (int kk = 0; kk < 4; ++kk) {
                const int c0 = kk * 8 + lg * 2;
                const float4 va = *(const float4*)(rb + ((c0 ^ rs) << 4));
                const float4 vb = *(const float4*)(rb + (((c0 + 1) ^ rs) << 4));
                union { bf16x8 v; uint u[4]; } fr;
                fr.u[0] = cvtpk_bf16(va.x, va.y);
                fr.u[1] = cvtpk_bf16(va.z, va.w);
                fr.u[2] = cvtpk_bf16(vb.x, vb.y);
                fr.u[3] = cvtpk_bf16(vb.z, vb.w);
                acc = __builtin_amdgcn_mfma_f32_16x16x32_bf16(w1f[kk], fr.v, acc, 0, 0, 0);
            }
            // silu + W2 partial over this wave's 16 hids (4 per lane, 4 lg groups)
            float p0 = 0, p1 = 0, p2 = 0, p3 = 0;
            #pragma unroll
            for (int r = 0; r < 4; ++r) {
                const float s = silu_f(acc[r]);
                p0 = fmaf(s, w2r[r][0], p0);
                p1 = fmaf(s, w2r[r][1], p1);
                p2 = fmaf(s, w2r[r][2], p2);
                p3 = fmaf(s, w2r[r][3], p3);
            }
            p0 += __shfl_xor(p0, 16); p0 += __shfl_xor(p0, 32);
            p1 += __shfl_xor(p1, 16); p1 += __shfl_xor(p1, 32);
            p2 += __shfl_xor(p2, 16); p2 += __shfl_xor(p2, 32);
            p3 += __shfl_xor(p3, 16); p3 += __shfl_xor(p3, 32);
            if (lane < 16) {
                float* d = &sP[(mh * TILE + ag * 16 + lane) * 5];
                d[0] = p0; d[1] = p1; d[2] = p2; d[3] = p3;
            }
        }
        // bar1: LDS-only fence (NO vmcnt drain -> DMA keeps streaming)
        asm volatile("s_waitcnt lgkmcnt(0)" ::: "memory");
        __builtin_amdgcn_s_barrier();

        // ---- D: defer-max online softmax (T13); wave wv = head wv, lane = atom ----
        {
            const float v = (lane < T)
                ? sP[lane * 5 + wv] + sP[(TILE + lane) * 5 + wv] + b2w
                : -INFINITY;
            if (__any(v > m_run + 8.0f)) {  // wave-uniform; rare after tile 0
                float mt = v;
                #pragma unroll
                for (int d = 1; d < 64; d <<= 1) mt = fmaxf(mt, __shfl_xor(mt, d));
                const float m_new = fmaxf(m_run, mt);
                const float r = __expf(m_run - m_new);  // first tile: exp(-inf)=0
                s_part *= r;
                #pragma unroll
                for (int j = 0; j < 8; ++j) acc8[j] *= r;
                m_run = m_new;
            }
            const float e = (lane < T) ? __expf(v - m_run) : 0.0f;  // bounded by e^8
            sTW[wv * 65 + lane] = e;  // own-wave region; same-wave read below
            s_part += e;
        }

        // ---- C: fp32 weighted accumulate; lane = (atom-off ca, oct co) ----
        {
            #pragma unroll 4
            for (int i = 0; i < 8; ++i) {
                const int a = i * 4 + ca;
                const float w = sTW[wv * 65 + a];
                const int sw = a & 7;
                const char* ra = bufc + a * ROWB;
                const float4 v0 = *(const float4*)(ra + (((2 * co) ^ sw) << 4));
                const float4 v1 = *(const float4*)(ra + (((2 * co + 1) ^ sw) << 4));
                acc8[0] = fmaf(w, v0.x, acc8[0]);
                acc8[1] = fmaf(w, v0.y, acc8[1]);
                acc8[2] = fmaf(w, v0.z, acc8[2]);
                acc8[3] = fmaf(w, v0.w, acc8[3]);
                acc8[4] = fmaf(w, v1.x, acc8[4]);
                acc8[5] = fmaf(w, v1.y, acc8[5]);
                acc8[6] = fmaf(w, v1.z, acc8[6]);
                acc8[7] = fmaf(w, v1.w, acc8[7]);
            }
        }
        __syncthreads();  // drains vmcnt(0): DMA(k+1) landed; buf[pb] reads done
        pb ^= 1;
    }

    // ---- epilogue 1: denom butterfly + atom-offset reduce -> normalized Wacc in LDS ----
    #pragma unroll
    for (int d = 1; d < 64; d <<= 1) s_part += __shfl_xor(s_part, d);
    const float inv = (s_part > 0.0f) ? 1.0f / s_part : 0.0f;
    #pragma unroll
    for (int j = 0; j < 8; ++j) {
        acc8[j] += __shfl_xor(acc8[j], 1);
        acc8[j] += __shfl_xor(acc8[j], 2);
    }
    float* sWacc = (float*)sStage;        // 512 floats, k = h*F + f (main loop done)
    float* sPart = (float*)sStage + 512;  // 256 floats
    if ((lane & 3) == 0) {
        float* dst = &sWacc[wv * F + (lane >> 2) * 8];
        dst[0] = acc8[0] * inv; dst[1] = acc8[1] * inv;
        dst[2] = acc8[2] * inv; dst[3] = acc8[3] * inv;
        dst[4] = acc8[4] * inv; dst[5] = acc8[5] * inv;
        dst[6] = acc8[6] * inv; dst[7] = acc8[7] * inv;
    }
    __syncthreads();

    // ---- epilogue 2: inline projection out[b] = silu(Wacc @ Wp + bp) ----
    {
        const int f = t & 127, half = t >> 7;
        float sum = 0.0f;
        const float* wp = Wp + (size_t)(half * 256) * F + f;  // lanes coalesced over f
        const float* wa = &sWacc[half * 256];
        for (int k0 = 0; k0 < 256; k0 += 8) {
            float wpv[8];
            #pragma unroll
            for (int u = 0; u < 8; ++u) wpv[u] = wp[(size_t)(k0 + u) * F];
            #pragma unroll
            for (int u = 0; u < 8; ++u) sum = fmaf(wa[k0 + u], wpv[u], sum);
        }
        sPart[t] = sum;
    }
    __syncthreads();
    if (t < 128) out[(size_t)b * F + t] = silu_f(sPart[t] + sPart[t + 128] + bp[t]);
}

extern "C" void kernel_launch(void* const* d_in, const int* in_sizes, int n_in,
                              void* d_out, int out_size, void* d_ws, size_t ws_size,
                              hipStream_t stream) {
    const float* atom_fea = (const float*)d_in[0];
    const int* seg = (const int*)d_in[1];
    const float* W1 = (const float*)d_in[3];
    const float* b1 = (const float*)d_in[4];
    const float* W2 = (const float*)d_in[5];
    const float* b2 = (const float*)d_in[6];
    const float* Wp = (const float*)d_in[7];
    const float* bp = (const float*)d_in[8];
    float* out = (float*)d_out;

    const int N = in_sizes[0] / F;
    const int B = out_size / F;

    fused17_kernel<<<B, 256, 0, stream>>>(atom_fea, seg, N, W1, b1, W2, b2, Wp, bp, out);
}